// Round 1
// baseline (219.054 us; speedup 1.0000x reference)
//
#include <hip/hip_runtime.h>
#include <math.h>

// Problem constants
namespace {
constexpr int kB  = 64;
constexpr int kNi = 2048;
constexpr int kDi = 8;
constexpr int kNo = 32;
constexpr int kDo = 16;

constexpr int kThreads   = 512;               // 8 waves
constexpr int kNChunks   = 128;               // n-chunks
constexpr int kNPerChunk = kNi / kNChunks;    // 16 n per workgroup
constexpr int kStageN    = 4;                 // n per LDS stage (64 KB)
constexpr int kStages    = kNPerChunk / kStageN;  // 4
constexpr int kWFloatsPerN = kNo * kDo * kDi; // 4096 floats = 16 KB
constexpr int kSeg = kNo * kDo;               // 512 floats per (b) s-slice
}

// ---------------------------------------------------------------------------
// Pass kernel: recompute x_hat tiles from W (LDS-staged) and accumulate
// s_partial[chunk][b][o][d] with coupling coefficients c = softmax(vsum·x_hat).
// PASS==0: c uniform (1/32 applied in reduce).
// Each wave: lane -> (o = lane&31, half = lane>>5 covering d in [half*8, half*8+8)).
// Wave owns 4 consecutive b's; W fragment (64 floats) register-resident per n.
// ---------------------------------------------------------------------------
template<int PASS>
__global__ __launch_bounds__(kThreads, 1)
void caps_pass(const float* __restrict__ xg, const float* __restrict__ Wg,
               const float* __restrict__ vsum, float* __restrict__ partial)
{
    __shared__ float lds[kStageN * kWFloatsPerN];   // 65536 B

    const int tid    = threadIdx.x;
    const int nchunk = blockIdx.x & (kNChunks - 1); // 0..127
    const int bg     = blockIdx.x >> 7;             // 0..1
    const int wv     = tid >> 6;                    // 0..7
    const int lane   = tid & 63;
    const int o      = lane & 31;
    const int half   = lane >> 5;
    const int bbase  = bg * 32 + wv * 4;            // 4 b's per wave

    float vs[4][8];
    float sacc[4][8];
#pragma unroll
    for (int b2 = 0; b2 < 4; ++b2) {
#pragma unroll
        for (int j = 0; j < 8; ++j) sacc[b2][j] = 0.0f;
        if (PASS > 0) {
            const float4* vp = reinterpret_cast<const float4*>(
                vsum + (size_t)(bbase + b2) * kSeg + o * kDo + half * 8);
            float4 a = vp[0], b4 = vp[1];
            vs[b2][0] = a.x;  vs[b2][1] = a.y;  vs[b2][2] = a.z;  vs[b2][3] = a.w;
            vs[b2][4] = b4.x; vs[b2][5] = b4.y; vs[b2][6] = b4.z; vs[b2][7] = b4.w;
        }
    }

    const float4* lds4 = reinterpret_cast<const float4*>(lds);

    for (int stage = 0; stage < kStages; ++stage) {
        __syncthreads();   // all waves done reading previous stage
        {
            const size_t n0 = (size_t)nchunk * kNPerChunk + stage * kStageN;
            const float4* src = reinterpret_cast<const float4*>(Wg) + n0 * (kWFloatsPerN / 4);
            float4* dst = reinterpret_cast<float4*>(lds);
#pragma unroll
            for (int k = 0; k < (kStageN * kWFloatsPerN / 4) / kThreads; ++k) {  // 8
                int idx = k * kThreads + tid;
                int swz = idx ^ ((idx >> 5) & 7);   // XOR-swizzle: bank-spread lanes by o
                dst[swz] = src[idx];
            }
        }
        __syncthreads();

        for (int nn = 0; nn < kStageN; ++nn) {
            // Load my W fragment: W[n, o, half*8 + dd, i] for dd,i in [0,8) -> 64 floats
            float wf[64];
            {
                const int base4 = nn * (kWFloatsPerN / 4) + o * 32 + half * 16;
#pragma unroll
                for (int j4 = 0; j4 < 16; ++j4) {
                    float4 w4 = lds4[(base4 + j4) ^ (o & 7)];
                    wf[j4 * 4 + 0] = w4.x; wf[j4 * 4 + 1] = w4.y;
                    wf[j4 * 4 + 2] = w4.z; wf[j4 * 4 + 3] = w4.w;
                }
            }
            const int n = nchunk * kNPerChunk + stage * kStageN + nn;

#pragma unroll
            for (int b2 = 0; b2 < 4; ++b2) {
                const int b = bbase + b2;
                const float4* xp = reinterpret_cast<const float4*>(
                    xg + ((size_t)b * kNi + n) * kDi);
                float4 xa = xp[0], xb = xp[1];
                float xr[8] = {xa.x, xa.y, xa.z, xa.w, xb.x, xb.y, xb.z, xb.w};

                // x_hat for my (o, d-half): 8 values
                float xh[8];
#pragma unroll
                for (int dd = 0; dd < 8; ++dd) {
                    float acc = 0.0f;
#pragma unroll
                    for (int i = 0; i < 8; ++i) acc = fmaf(xr[i], wf[dd * 8 + i], acc);
                    xh[dd] = acc;
                }

                float c;
                if (PASS == 0) {
                    c = 1.0f;  // uniform coupling; 1/32 applied in reduce
                } else {
                    // logit L[o] = sum_d vsum[b,o,d] * xh[b,n,o,d]
                    float pl = 0.0f;
#pragma unroll
                    for (int dd = 0; dd < 8; ++dd) pl = fmaf(vs[b2][dd], xh[dd], pl);
                    float L = pl + __shfl_xor(pl, 32);   // add other d-half
                    // softmax over o within each 32-lane half
                    float m = L;
#pragma unroll
                    for (int msk = 16; msk >= 1; msk >>= 1)
                        m = fmaxf(m, __shfl_xor(m, msk));
                    float e = __expf(L - m);
                    float sm = e;
#pragma unroll
                    for (int msk = 16; msk >= 1; msk >>= 1)
                        sm += __shfl_xor(sm, msk);
                    c = e / sm;
                }
#pragma unroll
                for (int dd = 0; dd < 8; ++dd)
                    sacc[b2][dd] = fmaf(c, xh[dd], sacc[b2][dd]);
            }
        }
    }

    // Flush partial s for my 4 b's: layout [chunk][b][lane][8] (lane-major, coalesced)
#pragma unroll
    for (int b2 = 0; b2 < 4; ++b2) {
        float* pp = partial + ((size_t)nchunk * kB + (bbase + b2)) * kSeg + lane * 8;
        reinterpret_cast<float4*>(pp)[0] =
            make_float4(sacc[b2][0], sacc[b2][1], sacc[b2][2], sacc[b2][3]);
        reinterpret_cast<float4*>(pp)[1] =
            make_float4(sacc[b2][4], sacc[b2][5], sacc[b2][6], sacc[b2][7]);
    }
}

// ---------------------------------------------------------------------------
// Reduce kernel: sum partials over chunks -> s[b,o,d]; squash; update vsum/out.
// Grid = 64 blocks (one per b), 512 threads. Thread t -> (lane = t>>3, j = t&7)
// i.e. element (o = (t>>3)&31, d = (t>>8)*8 + (t&7)).
// ---------------------------------------------------------------------------
template<int PASS>
__global__ __launch_bounds__(512, 1)
void caps_reduce(const float* __restrict__ partial, float* __restrict__ vsum,
                 float* __restrict__ out)
{
    const int b = blockIdx.x;
    const int t = threadIdx.x;

    const float* p = partial + (size_t)b * kSeg + t;
    float a0 = 0, a1 = 0, a2 = 0, a3 = 0;
    for (int wg = 0; wg < kNChunks; wg += 4) {
        a0 += p[(size_t)(wg + 0) * (kB * kSeg)];
        a1 += p[(size_t)(wg + 1) * (kB * kSeg)];
        a2 += p[(size_t)(wg + 2) * (kB * kSeg)];
        a3 += p[(size_t)(wg + 3) * (kB * kSeg)];
    }
    float s = (a0 + a1) + (a2 + a3);
    if (PASS == 0) s *= (1.0f / 32.0f);   // uniform coupling 1/No

    __shared__ float s_lds[512];
    __shared__ float f_lds[32];
    s_lds[t] = s;
    __syncthreads();
    if (t < 32) {
        float n2 = 0.0f;
#pragma unroll
        for (int d = 0; d < 16; ++d) {
            float val = s_lds[(d >> 3) * 256 + t * 8 + (d & 7)];
            n2 = fmaf(val, val, n2);
        }
        f_lds[t] = sqrtf(n2) / (1.0f + n2);   // ||s|| / (1 + ||s||^2)
    }
    __syncthreads();

    const int o = (t >> 3) & 31;
    const int d = ((t >> 8) << 3) | (t & 7);
    const float v = f_lds[o] * s;

    if (PASS == 0)      vsum[(size_t)b * kSeg + o * kDo + d] = v;
    else if (PASS == 1) vsum[(size_t)b * kSeg + o * kDo + d] += v;
    else                out[(size_t)b * kSeg + o * kDo + d] = v;
}

// ---------------------------------------------------------------------------
extern "C" void kernel_launch(void* const* d_in, const int* in_sizes, int n_in,
                              void* d_out, int out_size, void* d_ws, size_t ws_size,
                              hipStream_t stream)
{
    const float* x = (const float*)d_in[0];   // (64, 2048, 8)
    const float* W = (const float*)d_in[1];   // (2048, 32, 16, 8)
    float* out = (float*)d_out;               // (64, 32, 16)

    float* partial = (float*)d_ws;            // [128][64][512] = 16 MB
    float* vsum = (float*)((char*)d_ws + (size_t)kNChunks * kB * kSeg * sizeof(float));

    const dim3 gp(kNChunks * 2), bp(kThreads);
    const dim3 gr(kB), br(512);

    caps_pass<0><<<gp, bp, 0, stream>>>(x, W, vsum, partial);
    caps_reduce<0><<<gr, br, 0, stream>>>(partial, vsum, out);
    caps_pass<1><<<gp, bp, 0, stream>>>(x, W, vsum, partial);
    caps_reduce<1><<<gr, br, 0, stream>>>(partial, vsum, out);
    caps_pass<2><<<gp, bp, 0, stream>>>(x, W, vsum, partial);
    caps_reduce<2><<<gr, br, 0, stream>>>(partial, vsum, out);
}